// Round 5
// baseline (840.419 us; speedup 1.0000x reference)
//
#include <hip/hip_runtime.h>
#include <math.h>

typedef __attribute__((ext_vector_type(8))) short bf16x8;
typedef __attribute__((ext_vector_type(4))) float f32x4;
typedef __attribute__((ext_vector_type(4))) unsigned short us4;
typedef __attribute__((ext_vector_type(8))) unsigned short us8;

constexpr int BB = 2;
constexpr int CC = 128;
constexpr int HH = 96, WW = 96;
constexpr int PP = HH * WW;        // 9216
constexpr int NN = BB * PP;        // 18432 pixels total
constexpr int CONV_BLKS = NN / 48; // 384

__device__ __forceinline__ float bf2f(unsigned short u) {
    return __uint_as_float(((unsigned)u) << 16);
}
__device__ __forceinline__ unsigned short f2bf(float f) {
    unsigned u = __float_as_uint(f);
    unsigned r = u + 0x7fff + ((u >> 16) & 1);
    return (unsigned short)(r >> 16);
}

// ---------------------------------------------------------------------------
// Weight conversion / reordering to bf16 (one dispatch).
// conv_w[L][o][c][ky][kx] -> wcv[L][o][t*128+c]  (t = ky*3+kx)
// qkv_w -> bf16 with q-rows (o<128) scaled by 0.25; fc/w_in/w_out direct.
// ---------------------------------------------------------------------------
__global__ __launch_bounds__(256)
void k_wconv(const float* __restrict__ conv_w, const float* __restrict__ qkv_w,
             const float* __restrict__ fc_w, const float* __restrict__ w_in,
             const float* __restrict__ w_out,
             unsigned short* __restrict__ wcv, unsigned short* __restrict__ wqkv,
             unsigned short* __restrict__ wfc, unsigned short* __restrict__ wi,
             unsigned short* __restrict__ wo)
{
    int gid = blockIdx.x * 256 + threadIdx.x;
    if (gid < 589824) {
        int L = gid / 147456, r = gid % 147456;
        int o = r / 1152, k = r % 1152;
        int t = k / 128, c = k % 128;
        float v = conv_w[(((size_t)(L * 128 + o) * 128 + c) * 9) + t];
        wcv[gid] = f2bf(v);
    } else if (gid < 786432) {
        int g = gid - 589824;
        int o = (g % 49152) / 128;
        float v = qkv_w[g] * (o < 128 ? 0.25f : 1.0f);
        wqkv[g] = f2bf(v);
    } else if (gid < 851968) {
        int g = gid - 786432;
        wfc[g] = f2bf(fc_w[g]);
    } else if (gid < 860160) {
        int g = gid - 851968;
        wi[g] = f2bf(w_in[g]);
    } else if (gid < 868352) {
        int g = gid - 860160;
        wo[g] = f2bf(w_out[g]);
    }
}

// x (fp32 [b][64][9216]) -> xT (bf16 [n][64])
__global__ __launch_bounds__(256)
void k_xconv(const float* __restrict__ x, unsigned short* __restrict__ xT)
{
    int n = blockIdx.x * 256 + threadIdx.x;
    int b = n / PP, p = n - b * PP;
    unsigned short* dst = xT + (size_t)n * 64;
    #pragma unroll
    for (int cg = 0; cg < 16; ++cg) {
        us4 st;
        #pragma unroll
        for (int r = 0; r < 4; ++r)
            st[r] = f2bf(x[((size_t)(b * 64 + cg * 4 + r)) * PP + p]);
        *reinterpret_cast<us4*>(dst + cg * 4) = st;
    }
}

// ---------------------------------------------------------------------------
// Dilated conv3x3 as implicit GEMM, in-block K-split.
// Block: 384 threads = 6 waves = 2 M-halves (wm) x 3 tap-groups (wz).
// Tile: 128 out-ch x 48 pixels. Grid: 384 blocks.
// Each wave: acc[4][3] over taps [3*wz, 3*wz+3), K=128 per tap.
// LDS reduce (elem-major, conflict-free) -> wz==0 waves hold full sums.
// Epilogue: y f32 [n][128] single plane + per-block BN channel partials
// (sum, sumsq over the block's 48 pixels) -> parts[blk][256].
// ---------------------------------------------------------------------------
template<int DIL>
__global__ __launch_bounds__(384)
void k_conv(const unsigned short* __restrict__ W,
            const unsigned short* __restrict__ act,
            float* __restrict__ y,
            float* __restrict__ parts,
            const unsigned short* __restrict__ zp)
{
    int tid = threadIdx.x;
    int lane = tid & 63, wv = tid >> 6;
    int wm = wv & 1, wz = wv >> 1;       // wm: M half, wz: tap group
    int l15 = lane & 15, kg = lane >> 4;

    int n_base = blockIdx.x * 48;
    int o_base = wm * 64;

    const unsigned short* wbase[4];
    #pragma unroll
    for (int fm = 0; fm < 4; ++fm)
        wbase[fm] = W + (size_t)(o_base + fm * 16 + l15) * 1152 + kg * 8;

    const unsigned short* bbase[3];
    int iF[3], jF[3];
    #pragma unroll
    for (int fn = 0; fn < 3; ++fn) {
        int n = n_base + fn * 16 + l15;
        bbase[fn] = act + (size_t)n * 128 + kg * 8;
        int pix = n % PP;
        iF[fn] = pix / WW;
        jF[fn] = pix % WW;
    }

    f32x4 acc[4][3];
    #pragma unroll
    for (int fm = 0; fm < 4; ++fm)
        #pragma unroll
        for (int fn = 0; fn < 3; ++fn)
            acc[fm][fn] = (f32x4){0.f, 0.f, 0.f, 0.f};

    const unsigned short* zpk = zp + kg * 8;
    int t0 = wz * 3;
    #pragma unroll
    for (int tt = 0; tt < 3; ++tt) {
        int t = t0 + tt;
        int oy = (t / 3 - 1) * DIL, ox = (t % 3 - 1) * DIL;
        int disp = (oy * WW + ox) * 128;
        const unsigned short* baddr[3];
        #pragma unroll
        for (int fn = 0; fn < 3; ++fn) {
            bool v = ((unsigned)(iF[fn] + oy) < (unsigned)HH) &&
                     ((unsigned)(jF[fn] + ox) < (unsigned)WW);
            baddr[fn] = v ? (bbase[fn] + disp) : zpk;
        }
        #pragma unroll
        for (int c0 = 0; c0 < 128; c0 += 32) {
            bf16x8 a[4], b[3];
            #pragma unroll
            for (int fm = 0; fm < 4; ++fm)
                a[fm] = *reinterpret_cast<const bf16x8*>(wbase[fm] + t * 128 + c0);
            #pragma unroll
            for (int fn = 0; fn < 3; ++fn)
                b[fn] = *reinterpret_cast<const bf16x8*>(baddr[fn] + c0);
            #pragma unroll
            for (int fm = 0; fm < 4; ++fm)
                #pragma unroll
                for (int fn = 0; fn < 3; ++fn)
                    acc[fm][fn] = __builtin_amdgcn_mfma_f32_16x16x32_bf16(
                        a[fm], b[fn], acc[fm][fn], 0, 0, 0);
        }
    }

    // LDS reduction: waves wz=1,2 deposit; wz=0 accumulates.
    // elem-major [slot][elem][lane] -> conflict-free b32 accesses.
    __shared__ float red[4][48][64];
    if (wz) {
        int s = wm * 2 + wz - 1;
        #pragma unroll
        for (int fm = 0; fm < 4; ++fm)
            #pragma unroll
            for (int fn = 0; fn < 3; ++fn)
                #pragma unroll
                for (int r = 0; r < 4; ++r)
                    red[s][fm * 12 + fn * 4 + r][lane] = acc[fm][fn][r];
    }
    __syncthreads();
    if (wz == 0) {
        #pragma unroll
        for (int fm = 0; fm < 4; ++fm)
            #pragma unroll
            for (int fn = 0; fn < 3; ++fn)
                #pragma unroll
                for (int r = 0; r < 4; ++r)
                    acc[fm][fn][r] += red[wm * 2][fm * 12 + fn * 4 + r][lane] +
                                      red[wm * 2 + 1][fm * 12 + fn * 4 + r][lane];

        // write y (f32, [n][128])
        #pragma unroll
        for (int fm = 0; fm < 4; ++fm) {
            int o0 = o_base + fm * 16 + kg * 4;
            #pragma unroll
            for (int fn = 0; fn < 3; ++fn) {
                int n = n_base + fn * 16 + l15;
                *reinterpret_cast<f32x4*>(y + (size_t)n * 128 + o0) = acc[fm][fn];
            }
        }

        // BN partials: per channel sum/sumsq over this block's 48 pixels.
        #pragma unroll
        for (int fm = 0; fm < 4; ++fm) {
            #pragma unroll
            for (int r = 0; r < 4; ++r) {
                float s = 0.f, s2 = 0.f;
                #pragma unroll
                for (int fn = 0; fn < 3; ++fn) {
                    float v = acc[fm][fn][r];
                    s += v; s2 += v * v;
                }
                #pragma unroll
                for (int m = 1; m <= 8; m <<= 1) {
                    s  += __shfl_xor(s,  m, 64);
                    s2 += __shfl_xor(s2, m, 64);
                }
                if (l15 == 0) {
                    int c = o_base + fm * 16 + kg * 4 + r;
                    parts[(size_t)blockIdx.x * 256 + c]       = s;
                    parts[(size_t)blockIdx.x * 256 + 128 + c] = s2;
                }
            }
        }
    }
}

// ---------------------------------------------------------------------------
// MFMA GEMM for 1x1 convs: out[o][n] = sum_k W[o][k] * act[n][k]
// MODE 0: bf16 out [n][Cout] (+bias)
// MODE 2: bf16 out [n][Cout] + bias + bf16 residual
// MODE 3: f32 out [b][Cout][9216] scatter + bias (final projection)
// ---------------------------------------------------------------------------
template<int WM, int WN, int MODE>
__global__ __launch_bounds__(WM * WN * 64)
void k_gemm(const unsigned short* __restrict__ W,
            const unsigned short* __restrict__ act,
            const float* __restrict__ bias,
            const unsigned short* __restrict__ resid,
            void* __restrict__ outp,
            int Kw, int Cin, int Cout)
{
    int tid = threadIdx.x;
    int lane = tid & 63, wv = tid >> 6;
    int wm = wv % WM, wn = wv / WM;
    int l15 = lane & 15, kg = lane >> 4;

    int n_base = blockIdx.x * (WN * 96) + wn * 96;
    int o_base = blockIdx.y * (WM * 64) + wm * 64;

    const unsigned short* wbase[4];
    #pragma unroll
    for (int fm = 0; fm < 4; ++fm) {
        int o = o_base + fm * 16 + l15;
        wbase[fm] = W + (size_t)o * Kw + kg * 8;
    }

    const unsigned short* bbase[6];
    #pragma unroll
    for (int fn = 0; fn < 6; ++fn) {
        int n = n_base + fn * 16 + l15;
        bbase[fn] = act + (size_t)n * Cin + kg * 8;
    }

    f32x4 acc[4][6];
    #pragma unroll
    for (int fm = 0; fm < 4; ++fm)
        #pragma unroll
        for (int fn = 0; fn < 6; ++fn)
            acc[fm][fn] = (f32x4){0.f, 0.f, 0.f, 0.f};

    #pragma unroll
    for (int k0 = 0; k0 < 128; k0 += 32) {
        if (k0 >= Cin) break;
        bf16x8 a[4], b[6];
        #pragma unroll
        for (int fm = 0; fm < 4; ++fm)
            a[fm] = *reinterpret_cast<const bf16x8*>(wbase[fm] + k0);
        #pragma unroll
        for (int fn = 0; fn < 6; ++fn)
            b[fn] = *reinterpret_cast<const bf16x8*>(bbase[fn] + k0);
        #pragma unroll
        for (int fm = 0; fm < 4; ++fm)
            #pragma unroll
            for (int fn = 0; fn < 6; ++fn)
                acc[fm][fn] = __builtin_amdgcn_mfma_f32_16x16x32_bf16(
                    a[fm], b[fn], acc[fm][fn], 0, 0, 0);
    }

    #pragma unroll
    for (int fm = 0; fm < 4; ++fm) {
        #pragma unroll
        for (int fn = 0; fn < 6; ++fn) {
            f32x4 v = acc[fm][fn];
            int n = n_base + fn * 16 + l15;
            int o0 = o_base + fm * 16 + kg * 4;
            if constexpr (MODE == 0 || MODE == 2) {
                if (bias) {
                    #pragma unroll
                    for (int r = 0; r < 4; ++r) v[r] += bias[o0 + r];
                }
                if constexpr (MODE == 2) {
                    us4 rv = *reinterpret_cast<const us4*>(resid + (size_t)n * Cout + o0);
                    #pragma unroll
                    for (int r = 0; r < 4; ++r) v[r] += bf2f(rv[r]);
                }
                us4 st;
                #pragma unroll
                for (int r = 0; r < 4; ++r) st[r] = f2bf(v[r]);
                *reinterpret_cast<us4*>((unsigned short*)outp + (size_t)n * Cout + o0) = st;
            } else {
                int b_ = n / PP, p = n - b_ * PP;
                float* op = (float*)outp;
                #pragma unroll
                for (int r = 0; r < 4; ++r)
                    op[((size_t)(b_ * Cout + o0 + r)) * PP + p] = v[r] + bias[o0 + r];
            }
        }
    }
}

// Finalize BN: reduce per-block partials, compute scale/shift per channel.
__global__ __launch_bounds__(128)
void k_bnfin(const float* __restrict__ partials, const float* __restrict__ g,
             const float* __restrict__ b, float* __restrict__ scsh, int nblk)
{
    int c = threadIdx.x;
    float S = 0.f, S2 = 0.f;
    for (int blk = 0; blk < nblk; ++blk) {
        S  += partials[(size_t)blk * 256 + c];
        S2 += partials[(size_t)blk * 256 + 128 + c];
    }
    const float inv = 1.f / (float)NN;
    float mu = S * inv;
    float var = S2 * inv - mu * mu;
    float sc = g[c] * rsqrtf(var + 1e-5f);
    scsh[c] = sc;
    scsh[128 + c] = b[c] - mu * sc;
}

// BN apply + ReLU: y f32 [n][128] -> h bf16 [n][128]
__global__ __launch_bounds__(256)
void k_bnrelu(const float* __restrict__ y, const float* __restrict__ scsh,
              unsigned short* __restrict__ h)
{
    int gid = blockIdx.x * 256 + threadIdx.x;   // quads
    int c0 = (gid * 4) & 127;
    size_t idx = (size_t)gid * 4;
    f32x4 v = *reinterpret_cast<const f32x4*>(y + idx);
    us4 st;
    #pragma unroll
    for (int r = 0; r < 4; ++r) {
        float f = fmaxf(fmaf(v[r], scsh[c0 + r], scsh[128 + c0 + r]), 0.f);
        st[r] = f2bf(f);
    }
    *reinterpret_cast<us4*>(h + idx) = st;
}

// ---------------------------------------------------------------------------
// Local channel self-attention, spill-free.
// Thread = (pixel n, head, ng): owns 4 q-channels vs all 16 m-channels.
// ---------------------------------------------------------------------------
__global__ __launch_bounds__(256)
void k_attn(const unsigned short* __restrict__ qkv, unsigned short* __restrict__ att)
{
    int gid = blockIdx.x * 256 + threadIdx.x;   // 589824
    int ng   = gid & 3;
    int head = (gid >> 2) & 7;
    int n    = gid >> 5;
    int pix = n % PP;
    int i = pix / WW, j = pix % WW;
    int hc = head * 16;
    const unsigned short* base = qkv + (size_t)n * 384;

    float dots[4][16];
    float vs[16];
    #pragma unroll
    for (int m = 0; m < 16; ++m) vs[m] = 0.f;
    #pragma unroll
    for (int nn = 0; nn < 4; ++nn)
        #pragma unroll
        for (int m = 0; m < 16; ++m) dots[nn][m] = 0.f;

    #pragma unroll
    for (int dy = 0; dy < 3; ++dy) {
        #pragma unroll
        for (int dx = 0; dx < 3; ++dx) {
            if (!(((unsigned)(i + dy - 1) < (unsigned)HH) &&
                  ((unsigned)(j + dx - 1) < (unsigned)WW))) continue;
            const unsigned short* pb = base + ((dy - 1) * WW + (dx - 1)) * 384;
            us4 q4 = *reinterpret_cast<const us4*>(pb + hc + ng * 4);
            us8 k0 = *reinterpret_cast<const us8*>(pb + 128 + hc);
            us8 k1 = *reinterpret_cast<const us8*>(pb + 128 + hc + 8);
            us8 v0 = *reinterpret_cast<const us8*>(pb + 256 + hc);
            us8 v1 = *reinterpret_cast<const us8*>(pb + 256 + hc + 8);
            float kf[16];
            #pragma unroll
            for (int e = 0; e < 8; ++e) {
                kf[e] = bf2f(k0[e]);
                kf[8 + e] = bf2f(k1[e]);
                vs[e] += bf2f(v0[e]);
                vs[8 + e] += bf2f(v1[e]);
            }
            #pragma unroll
            for (int nn = 0; nn < 4; ++nn) {
                float qf = bf2f(q4[nn]);
                #pragma unroll
                for (int m = 0; m < 16; ++m)
                    dots[nn][m] = fmaf(qf, kf[m], dots[nn][m]);
            }
        }
    }

    us4 st;
    #pragma unroll
    for (int nn = 0; nn < 4; ++nn) {
        float mx = dots[nn][0];
        #pragma unroll
        for (int m = 1; m < 16; ++m) mx = fmaxf(mx, dots[nn][m]);
        float den = 0.f, o = 0.f;
        #pragma unroll
        for (int m = 0; m < 16; ++m) {
            float e = __expf(dots[nn][m] - mx);
            den += e;
            o = fmaf(e, vs[m], o);
        }
        st[nn] = f2bf(o / den);
    }
    *reinterpret_cast<us4*>(att + (size_t)n * CC + hc + ng * 4) = st;
}

// ---------------------------------------------------------------------------
extern "C" void kernel_launch(void* const* d_in, const int* in_sizes, int n_in,
                              void* d_out, int out_size, void* d_ws, size_t ws_size,
                              hipStream_t stream)
{
    const float* x      = (const float*)d_in[0];
    const float* w_in   = (const float*)d_in[1];
    const float* b_in   = (const float*)d_in[2];
    const float* conv_w = (const float*)d_in[3];
    const float* bn_g   = (const float*)d_in[5];
    const float* bn_b   = (const float*)d_in[6];
    const float* qkv_w  = (const float*)d_in[7];
    const float* fc_w   = (const float*)d_in[8];
    const float* fc_b   = (const float*)d_in[9];
    const float* w_out  = (const float*)d_in[10];
    const float* b_out  = (const float*)d_in[11];

    char* ws = (char*)d_ws;
    unsigned short* zp    = (unsigned short*)(ws);                   // 4 KB zeros
    unsigned short* wcv   = (unsigned short*)(ws + 4096);            // 1,179,648
    unsigned short* wqkv  = (unsigned short*)(ws + 1183744);         //   393,216
    unsigned short* wfc   = (unsigned short*)(ws + 1576960);         //   131,072
    unsigned short* wi    = (unsigned short*)(ws + 1708032);         //    16,384
    unsigned short* wo    = (unsigned short*)(ws + 1724416);         //    16,384
    unsigned short* xT    = (unsigned short*)(ws + 1740800);         // 2,359,296
    unsigned short* bufA  = (unsigned short*)(ws + 4100096);         // 4,718,592
    float*          ybuf  = (float*)        (ws + 8818688);          // 9,437,184
    unsigned short* hbuf  = (unsigned short*)(ws + 18255872);        // 4,718,592
    unsigned short* qkvb  = (unsigned short*)(ws + 22974464);        // 14,155,776
    unsigned short* attb  = (unsigned short*)(ws + 37130240);        // 4,718,592
    float*          parts = (float*)        (ws + 41848832);         //   393,216
    float*          scsh  = (float*)        (ws + 42242048);         //     1,024

    hipMemsetAsync(zp, 0, 4096, stream);

    k_wconv<<<3392, 256, 0, stream>>>(conv_w, qkv_w, fc_w, w_in, w_out,
                                      wcv, wqkv, wfc, wi, wo);
    k_xconv<<<NN / 256, 256, 0, stream>>>(x, xT);

    // in-proj: 64 -> 128, bias -> bufA (bf16)
    k_gemm<1, 2, 0><<<dim3(96, 2), 128, 0, stream>>>(
        wi, xT, b_in, nullptr, bufA, 64, 64, 128);

    for (int L = 0; L < 4; ++L) {
        const unsigned short* wc = wcv + (size_t)L * 147456;
        // dilated conv3x3 -> single f32 plane + BN partials
        switch (L) {
            case 0: k_conv<1><<<CONV_BLKS, 384, 0, stream>>>(wc, bufA, ybuf, parts, zp); break;
            case 1: k_conv<2><<<CONV_BLKS, 384, 0, stream>>>(wc, bufA, ybuf, parts, zp); break;
            case 2: k_conv<4><<<CONV_BLKS, 384, 0, stream>>>(wc, bufA, ybuf, parts, zp); break;
            case 3: k_conv<8><<<CONV_BLKS, 384, 0, stream>>>(wc, bufA, ybuf, parts, zp); break;
        }
        k_bnfin<<<1, 128, 0, stream>>>(parts, bn_g + L * 128, bn_b + L * 128, scsh, CONV_BLKS);
        k_bnrelu<<<2304, 256, 0, stream>>>(ybuf, scsh, hbuf);

        // qkv: 128 -> 384 -> qkvb
        k_gemm<1, 2, 0><<<dim3(96, 6), 128, 0, stream>>>(
            wqkv + (size_t)L * 49152, hbuf, nullptr, nullptr, qkvb, 128, 128, 384);

        k_attn<<<2304, 256, 0, stream>>>(qkvb, attb);

        // fc: 128 -> 128 + bias + residual(hbuf) -> bufA
        k_gemm<1, 2, 2><<<dim3(96, 2), 128, 0, stream>>>(
            wfc + (size_t)L * 16384, attb, fc_b + L * 128, hbuf, bufA, 128, 128, 128);
    }

    // out-proj: 128 -> 64, bias, f32 scatter to d_out
    k_gemm<1, 2, 3><<<dim3(96, 1), 128, 0, stream>>>(
        wo, bufA, b_out, nullptr, (float*)d_out, 128, 128, 64);
}

// Round 6
// 465.399 us; speedup vs baseline: 1.8058x; 1.8058x over previous
//
#include <hip/hip_runtime.h>
#include <math.h>

typedef __attribute__((ext_vector_type(8))) short bf16x8;
typedef __attribute__((ext_vector_type(4))) float f32x4;
typedef __attribute__((ext_vector_type(4))) unsigned short us4;
typedef __attribute__((ext_vector_type(8))) unsigned short us8;

constexpr int BB = 2;
constexpr int CC = 128;
constexpr int HH = 96, WW = 96;
constexpr int PP = HH * WW;        // 9216
constexpr int NN = BB * PP;        // 18432 pixels total
constexpr int CONV_BLKS = NN / 48; // 384

__device__ __forceinline__ float bf2f(unsigned short u) {
    return __uint_as_float(((unsigned)u) << 16);
}
__device__ __forceinline__ unsigned short f2bf(float f) {
    unsigned u = __float_as_uint(f);
    unsigned r = u + 0x7fff + ((u >> 16) & 1);
    return (unsigned short)(r >> 16);
}

// ---------------------------------------------------------------------------
// Weight conversion / reordering to bf16 (one dispatch).
// conv_w[L][o][c][ky][kx] -> wcv[L][o][t*128+c]  (t = ky*3+kx)
// qkv_w -> bf16 with q-rows (o<128) scaled by 0.25; fc/w_in/w_out direct.
// ---------------------------------------------------------------------------
__global__ __launch_bounds__(256)
void k_wconv(const float* __restrict__ conv_w, const float* __restrict__ qkv_w,
             const float* __restrict__ fc_w, const float* __restrict__ w_in,
             const float* __restrict__ w_out,
             unsigned short* __restrict__ wcv, unsigned short* __restrict__ wqkv,
             unsigned short* __restrict__ wfc, unsigned short* __restrict__ wi,
             unsigned short* __restrict__ wo)
{
    int gid = blockIdx.x * 256 + threadIdx.x;
    if (gid < 589824) {
        int L = gid / 147456, r = gid % 147456;
        int o = r / 1152, k = r % 1152;
        int t = k / 128, c = k % 128;
        float v = conv_w[(((size_t)(L * 128 + o) * 128 + c) * 9) + t];
        wcv[gid] = f2bf(v);
    } else if (gid < 786432) {
        int g = gid - 589824;
        int o = (g % 49152) / 128;
        float v = qkv_w[g] * (o < 128 ? 0.25f : 1.0f);
        wqkv[g] = f2bf(v);
    } else if (gid < 851968) {
        int g = gid - 786432;
        wfc[g] = f2bf(fc_w[g]);
    } else if (gid < 860160) {
        int g = gid - 851968;
        wi[g] = f2bf(w_in[g]);
    } else if (gid < 868352) {
        int g = gid - 860160;
        wo[g] = f2bf(w_out[g]);
    }
}

// x (fp32 [b][64][9216]) -> xT (bf16 [n][64])
__global__ __launch_bounds__(256)
void k_xconv(const float* __restrict__ x, unsigned short* __restrict__ xT)
{
    int n = blockIdx.x * 256 + threadIdx.x;
    int b = n / PP, p = n - b * PP;
    unsigned short* dst = xT + (size_t)n * 64;
    #pragma unroll
    for (int cg = 0; cg < 16; ++cg) {
        us4 st;
        #pragma unroll
        for (int r = 0; r < 4; ++r)
            st[r] = f2bf(x[((size_t)(b * 64 + cg * 4 + r)) * PP + p]);
        *reinterpret_cast<us4*>(dst + cg * 4) = st;
    }
}

// ---------------------------------------------------------------------------
// Dilated conv3x3 as implicit GEMM, in-block K-split.
// Block: 384 threads = 6 waves = 2 M-halves (wm) x 3 tap-groups (wz).
// Tile: 128 out-ch x 48 pixels. Grid: 384 blocks.
// LDS reduce -> single f32 y plane + per-block BN channel partials.
// ---------------------------------------------------------------------------
template<int DIL>
__global__ __launch_bounds__(384)
void k_conv(const unsigned short* __restrict__ W,
            const unsigned short* __restrict__ act,
            float* __restrict__ y,
            float* __restrict__ parts,
            const unsigned short* __restrict__ zp)
{
    int tid = threadIdx.x;
    int lane = tid & 63, wv = tid >> 6;
    int wm = wv & 1, wz = wv >> 1;       // wm: M half, wz: tap group
    int l15 = lane & 15, kg = lane >> 4;

    int n_base = blockIdx.x * 48;
    int o_base = wm * 64;

    const unsigned short* wbase[4];
    #pragma unroll
    for (int fm = 0; fm < 4; ++fm)
        wbase[fm] = W + (size_t)(o_base + fm * 16 + l15) * 1152 + kg * 8;

    const unsigned short* bbase[3];
    int iF[3], jF[3];
    #pragma unroll
    for (int fn = 0; fn < 3; ++fn) {
        int n = n_base + fn * 16 + l15;
        bbase[fn] = act + (size_t)n * 128 + kg * 8;
        int pix = n % PP;
        iF[fn] = pix / WW;
        jF[fn] = pix % WW;
    }

    f32x4 acc[4][3];
    #pragma unroll
    for (int fm = 0; fm < 4; ++fm)
        #pragma unroll
        for (int fn = 0; fn < 3; ++fn)
            acc[fm][fn] = (f32x4){0.f, 0.f, 0.f, 0.f};

    const unsigned short* zpk = zp + kg * 8;
    int t0 = wz * 3;
    #pragma unroll
    for (int tt = 0; tt < 3; ++tt) {
        int t = t0 + tt;
        int oy = (t / 3 - 1) * DIL, ox = (t % 3 - 1) * DIL;
        int disp = (oy * WW + ox) * 128;
        const unsigned short* baddr[3];
        #pragma unroll
        for (int fn = 0; fn < 3; ++fn) {
            bool v = ((unsigned)(iF[fn] + oy) < (unsigned)HH) &&
                     ((unsigned)(jF[fn] + ox) < (unsigned)WW);
            baddr[fn] = v ? (bbase[fn] + disp) : zpk;
        }
        #pragma unroll
        for (int c0 = 0; c0 < 128; c0 += 32) {
            bf16x8 a[4], b[3];
            #pragma unroll
            for (int fm = 0; fm < 4; ++fm)
                a[fm] = *reinterpret_cast<const bf16x8*>(wbase[fm] + t * 128 + c0);
            #pragma unroll
            for (int fn = 0; fn < 3; ++fn)
                b[fn] = *reinterpret_cast<const bf16x8*>(baddr[fn] + c0);
            #pragma unroll
            for (int fm = 0; fm < 4; ++fm)
                #pragma unroll
                for (int fn = 0; fn < 3; ++fn)
                    acc[fm][fn] = __builtin_amdgcn_mfma_f32_16x16x32_bf16(
                        a[fm], b[fn], acc[fm][fn], 0, 0, 0);
        }
    }

    __shared__ float red[4][48][64];
    if (wz) {
        int s = wm * 2 + wz - 1;
        #pragma unroll
        for (int fm = 0; fm < 4; ++fm)
            #pragma unroll
            for (int fn = 0; fn < 3; ++fn)
                #pragma unroll
                for (int r = 0; r < 4; ++r)
                    red[s][fm * 12 + fn * 4 + r][lane] = acc[fm][fn][r];
    }
    __syncthreads();
    if (wz == 0) {
        #pragma unroll
        for (int fm = 0; fm < 4; ++fm)
            #pragma unroll
            for (int fn = 0; fn < 3; ++fn)
                #pragma unroll
                for (int r = 0; r < 4; ++r)
                    acc[fm][fn][r] += red[wm * 2][fm * 12 + fn * 4 + r][lane] +
                                      red[wm * 2 + 1][fm * 12 + fn * 4 + r][lane];

        #pragma unroll
        for (int fm = 0; fm < 4; ++fm) {
            int o0 = o_base + fm * 16 + kg * 4;
            #pragma unroll
            for (int fn = 0; fn < 3; ++fn) {
                int n = n_base + fn * 16 + l15;
                *reinterpret_cast<f32x4*>(y + (size_t)n * 128 + o0) = acc[fm][fn];
            }
        }

        #pragma unroll
        for (int fm = 0; fm < 4; ++fm) {
            #pragma unroll
            for (int r = 0; r < 4; ++r) {
                float s = 0.f, s2 = 0.f;
                #pragma unroll
                for (int fn = 0; fn < 3; ++fn) {
                    float v = acc[fm][fn][r];
                    s += v; s2 += v * v;
                }
                #pragma unroll
                for (int m = 1; m <= 8; m <<= 1) {
                    s  += __shfl_xor(s,  m, 64);
                    s2 += __shfl_xor(s2, m, 64);
                }
                if (l15 == 0) {
                    int c = o_base + fm * 16 + kg * 4 + r;
                    parts[(size_t)blockIdx.x * 256 + c]       = s;
                    parts[(size_t)blockIdx.x * 256 + 128 + c] = s2;
                }
            }
        }
    }
}

// ---------------------------------------------------------------------------
// MFMA GEMM for 1x1 convs. Wave tile 64(M) x 16*F(N). Block = WM x WN waves.
// MODE 0: bf16 out [n][Cout] (+bias)
// MODE 2: bf16 out [n][Cout] + bias + bf16 residual
// MODE 3: f32 out [b][Cout][9216] scatter + bias (final projection)
// ---------------------------------------------------------------------------
template<int WM, int WN, int F, int MODE>
__global__ __launch_bounds__(WM * WN * 64)
void k_gemm(const unsigned short* __restrict__ W,
            const unsigned short* __restrict__ act,
            const float* __restrict__ bias,
            const unsigned short* __restrict__ resid,
            void* __restrict__ outp,
            int Kw, int Cin, int Cout)
{
    int tid = threadIdx.x;
    int lane = tid & 63, wv = tid >> 6;
    int wm = wv % WM, wn = wv / WM;
    int l15 = lane & 15, kg = lane >> 4;

    int n_base = blockIdx.x * (WN * 16 * F) + wn * 16 * F;
    int o_base = blockIdx.y * (WM * 64) + wm * 64;

    const unsigned short* wbase[4];
    #pragma unroll
    for (int fm = 0; fm < 4; ++fm) {
        int o = o_base + fm * 16 + l15;
        wbase[fm] = W + (size_t)o * Kw + kg * 8;
    }

    const unsigned short* bbase[F];
    #pragma unroll
    for (int fn = 0; fn < F; ++fn) {
        int n = n_base + fn * 16 + l15;
        bbase[fn] = act + (size_t)n * Cin + kg * 8;
    }

    f32x4 acc[4][F];
    #pragma unroll
    for (int fm = 0; fm < 4; ++fm)
        #pragma unroll
        for (int fn = 0; fn < F; ++fn)
            acc[fm][fn] = (f32x4){0.f, 0.f, 0.f, 0.f};

    #pragma unroll
    for (int k0 = 0; k0 < 128; k0 += 32) {
        if (k0 >= Cin) break;
        bf16x8 a[4], b[F];
        #pragma unroll
        for (int fm = 0; fm < 4; ++fm)
            a[fm] = *reinterpret_cast<const bf16x8*>(wbase[fm] + k0);
        #pragma unroll
        for (int fn = 0; fn < F; ++fn)
            b[fn] = *reinterpret_cast<const bf16x8*>(bbase[fn] + k0);
        #pragma unroll
        for (int fm = 0; fm < 4; ++fm)
            #pragma unroll
            for (int fn = 0; fn < F; ++fn)
                acc[fm][fn] = __builtin_amdgcn_mfma_f32_16x16x32_bf16(
                    a[fm], b[fn], acc[fm][fn], 0, 0, 0);
    }

    #pragma unroll
    for (int fm = 0; fm < 4; ++fm) {
        #pragma unroll
        for (int fn = 0; fn < F; ++fn) {
            f32x4 v = acc[fm][fn];
            int n = n_base + fn * 16 + l15;
            int o0 = o_base + fm * 16 + kg * 4;
            if constexpr (MODE == 0 || MODE == 2) {
                if (bias) {
                    #pragma unroll
                    for (int r = 0; r < 4; ++r) v[r] += bias[o0 + r];
                }
                if constexpr (MODE == 2) {
                    us4 rv = *reinterpret_cast<const us4*>(resid + (size_t)n * Cout + o0);
                    #pragma unroll
                    for (int r = 0; r < 4; ++r) v[r] += bf2f(rv[r]);
                }
                us4 st;
                #pragma unroll
                for (int r = 0; r < 4; ++r) st[r] = f2bf(v[r]);
                *reinterpret_cast<us4*>((unsigned short*)outp + (size_t)n * Cout + o0) = st;
            } else {
                int b_ = n / PP, p = n - b_ * PP;
                float* op = (float*)outp;
                #pragma unroll
                for (int r = 0; r < 4; ++r)
                    op[((size_t)(b_ * Cout + o0 + r)) * PP + p] = v[r] + bias[o0 + r];
            }
        }
    }
}

// ---------------------------------------------------------------------------
// Finalize BN: parallel reduce per-block partials -> scale/shift per channel.
// Grid: 128 blocks (one per channel) x 384 threads (one per conv block).
// ---------------------------------------------------------------------------
__global__ __launch_bounds__(384)
void k_bnfin(const float* __restrict__ partials, const float* __restrict__ g,
             const float* __restrict__ b, float* __restrict__ scsh)
{
    int c = blockIdx.x;
    int t = threadIdx.x;
    float s  = partials[(size_t)t * 256 + c];
    float s2 = partials[(size_t)t * 256 + 128 + c];
    #pragma unroll
    for (int m = 32; m > 0; m >>= 1) {
        s  += __shfl_down(s,  m, 64);
        s2 += __shfl_down(s2, m, 64);
    }
    __shared__ float ls[6], ls2[6];
    int wid = t >> 6;
    if ((t & 63) == 0) { ls[wid] = s; ls2[wid] = s2; }
    __syncthreads();
    if (t == 0) {
        float S = 0.f, S2 = 0.f;
        #pragma unroll
        for (int w = 0; w < 6; ++w) { S += ls[w]; S2 += ls2[w]; }
        const float inv = 1.f / (float)NN;
        float mu = S * inv;
        float var = S2 * inv - mu * mu;
        float sc = g[c] * rsqrtf(var + 1e-5f);
        scsh[c] = sc;
        scsh[128 + c] = b[c] - mu * sc;
    }
}

// BN apply + ReLU: y f32 [n][128] -> h bf16 [n][128]
__global__ __launch_bounds__(256)
void k_bnrelu(const float* __restrict__ y, const float* __restrict__ scsh,
              unsigned short* __restrict__ h)
{
    int gid = blockIdx.x * 256 + threadIdx.x;   // quads
    int c0 = (gid * 4) & 127;
    size_t idx = (size_t)gid * 4;
    f32x4 v = *reinterpret_cast<const f32x4*>(y + idx);
    us4 st;
    #pragma unroll
    for (int r = 0; r < 4; ++r) {
        float f = fmaxf(fmaf(v[r], scsh[c0 + r], scsh[128 + c0 + r]), 0.f);
        st[r] = f2bf(f);
    }
    *reinterpret_cast<us4*>(h + idx) = st;
}

// ---------------------------------------------------------------------------
// Local channel self-attention, spill-free.
// Thread = (pixel n, head, ng): owns 4 q-channels vs all 16 m-channels.
// ---------------------------------------------------------------------------
__global__ __launch_bounds__(256)
void k_attn(const unsigned short* __restrict__ qkv, unsigned short* __restrict__ att)
{
    int gid = blockIdx.x * 256 + threadIdx.x;   // 589824
    int ng   = gid & 3;
    int head = (gid >> 2) & 7;
    int n    = gid >> 5;
    int pix = n % PP;
    int i = pix / WW, j = pix % WW;
    int hc = head * 16;
    const unsigned short* base = qkv + (size_t)n * 384;

    float dots[4][16];
    float vs[16];
    #pragma unroll
    for (int m = 0; m < 16; ++m) vs[m] = 0.f;
    #pragma unroll
    for (int nn = 0; nn < 4; ++nn)
        #pragma unroll
        for (int m = 0; m < 16; ++m) dots[nn][m] = 0.f;

    #pragma unroll
    for (int dy = 0; dy < 3; ++dy) {
        #pragma unroll
        for (int dx = 0; dx < 3; ++dx) {
            if (!(((unsigned)(i + dy - 1) < (unsigned)HH) &&
                  ((unsigned)(j + dx - 1) < (unsigned)WW))) continue;
            const unsigned short* pb = base + ((dy - 1) * WW + (dx - 1)) * 384;
            us4 q4 = *reinterpret_cast<const us4*>(pb + hc + ng * 4);
            us8 k0 = *reinterpret_cast<const us8*>(pb + 128 + hc);
            us8 k1 = *reinterpret_cast<const us8*>(pb + 128 + hc + 8);
            us8 v0 = *reinterpret_cast<const us8*>(pb + 256 + hc);
            us8 v1 = *reinterpret_cast<const us8*>(pb + 256 + hc + 8);
            float kf[16];
            #pragma unroll
            for (int e = 0; e < 8; ++e) {
                kf[e] = bf2f(k0[e]);
                kf[8 + e] = bf2f(k1[e]);
                vs[e] += bf2f(v0[e]);
                vs[8 + e] += bf2f(v1[e]);
            }
            #pragma unroll
            for (int nn = 0; nn < 4; ++nn) {
                float qf = bf2f(q4[nn]);
                #pragma unroll
                for (int m = 0; m < 16; ++m)
                    dots[nn][m] = fmaf(qf, kf[m], dots[nn][m]);
            }
        }
    }

    us4 st;
    #pragma unroll
    for (int nn = 0; nn < 4; ++nn) {
        float mx = dots[nn][0];
        #pragma unroll
        for (int m = 1; m < 16; ++m) mx = fmaxf(mx, dots[nn][m]);
        float den = 0.f, o = 0.f;
        #pragma unroll
        for (int m = 0; m < 16; ++m) {
            float e = __expf(dots[nn][m] - mx);
            den += e;
            o = fmaf(e, vs[m], o);
        }
        st[nn] = f2bf(o / den);
    }
    *reinterpret_cast<us4*>(att + (size_t)n * CC + hc + ng * 4) = st;
}

// ---------------------------------------------------------------------------
extern "C" void kernel_launch(void* const* d_in, const int* in_sizes, int n_in,
                              void* d_out, int out_size, void* d_ws, size_t ws_size,
                              hipStream_t stream)
{
    const float* x      = (const float*)d_in[0];
    const float* w_in   = (const float*)d_in[1];
    const float* b_in   = (const float*)d_in[2];
    const float* conv_w = (const float*)d_in[3];
    const float* bn_g   = (const float*)d_in[5];
    const float* bn_b   = (const float*)d_in[6];
    const float* qkv_w  = (const float*)d_in[7];
    const float* fc_w   = (const float*)d_in[8];
    const float* fc_b   = (const float*)d_in[9];
    const float* w_out  = (const float*)d_in[10];
    const float* b_out  = (const float*)d_in[11];

    char* ws = (char*)d_ws;
    unsigned short* zp    = (unsigned short*)(ws);                   // 4 KB zeros
    unsigned short* wcv   = (unsigned short*)(ws + 4096);
    unsigned short* wqkv  = (unsigned short*)(ws + 1183744);
    unsigned short* wfc   = (unsigned short*)(ws + 1576960);
    unsigned short* wi    = (unsigned short*)(ws + 1708032);
    unsigned short* wo    = (unsigned short*)(ws + 1724416);
    unsigned short* xT    = (unsigned short*)(ws + 1740800);
    unsigned short* bufA  = (unsigned short*)(ws + 4100096);
    float*          ybuf  = (float*)        (ws + 8818688);
    unsigned short* hbuf  = (unsigned short*)(ws + 18255872);
    unsigned short* qkvb  = (unsigned short*)(ws + 22974464);
    unsigned short* attb  = (unsigned short*)(ws + 37130240);
    float*          parts = (float*)        (ws + 41848832);
    float*          scsh  = (float*)        (ws + 42242048);

    hipMemsetAsync(zp, 0, 4096, stream);

    k_wconv<<<3392, 256, 0, stream>>>(conv_w, qkv_w, fc_w, w_in, w_out,
                                      wcv, wqkv, wfc, wi, wo);
    k_xconv<<<NN / 256, 256, 0, stream>>>(x, xT);

    // in-proj: 64 -> 128, bias -> bufA (bf16)
    k_gemm<1, 2, 3, 0><<<dim3(192, 2), 128, 0, stream>>>(
        wi, xT, b_in, nullptr, bufA, 64, 64, 128);

    for (int L = 0; L < 4; ++L) {
        const unsigned short* wc = wcv + (size_t)L * 147456;
        switch (L) {
            case 0: k_conv<1><<<CONV_BLKS, 384, 0, stream>>>(wc, bufA, ybuf, parts, zp); break;
            case 1: k_conv<2><<<CONV_BLKS, 384, 0, stream>>>(wc, bufA, ybuf, parts, zp); break;
            case 2: k_conv<4><<<CONV_BLKS, 384, 0, stream>>>(wc, bufA, ybuf, parts, zp); break;
            case 3: k_conv<8><<<CONV_BLKS, 384, 0, stream>>>(wc, bufA, ybuf, parts, zp); break;
        }
        k_bnfin<<<128, 384, 0, stream>>>(parts, bn_g + L * 128, bn_b + L * 128, scsh);
        k_bnrelu<<<2304, 256, 0, stream>>>(ybuf, scsh, hbuf);

        // qkv: 128 -> 384 -> qkvb
        k_gemm<1, 2, 3, 0><<<dim3(192, 6), 128, 0, stream>>>(
            wqkv + (size_t)L * 49152, hbuf, nullptr, nullptr, qkvb, 128, 128, 384);

        k_attn<<<2304, 256, 0, stream>>>(qkvb, attb);

        // fc: 128 -> 128 + bias + residual(hbuf) -> bufA
        k_gemm<1, 2, 3, 2><<<dim3(192, 2), 128, 0, stream>>>(
            wfc + (size_t)L * 16384, attb, fc_b + L * 128, hbuf, bufA, 128, 128, 128);
    }

    // out-proj: 128 -> 64, bias, f32 scatter to d_out
    k_gemm<1, 2, 3, 3><<<dim3(192, 1), 128, 0, stream>>>(
        wo, bufA, b_out, nullptr, (float*)d_out, 128, 128, 64);
}